// Round 5
// baseline (31.962 us; speedup 1.0000x reference)
//
#include <hip/hip_runtime.h>

// Problem constants (match reference: B=8, N=8192, D=256, M=2)
#define NN 8192
#define DD 256
#define NH (NN / 2)
#define BB 8
#define RPW 16   // output rows per wave
#define WPB 4    // waves per block
#define NBLK (BB * NN / RPW / WPB)   // 1024
#define CPX (NBLK / 8)               // blocks per XCD chunk = 128 (== one batch b)

typedef float fx4 __attribute__((ext_vector_type(4)));  // native vec for nontemporal builtin

__device__ __forceinline__ float4 f4_load(const float* p) {
    return *reinterpret_cast<const float4*>(p);
}
__device__ __forceinline__ float4 f4_scale(float s, float4 v) {
    return make_float4(s * v.x, s * v.y, s * v.z, s * v.w);
}
__device__ __forceinline__ float4 f4_fma(float s, float4 v, float4 a) {
    return make_float4(fmaf(s, v.x, a.x), fmaf(s, v.y, a.y),
                       fmaf(s, v.z, a.z), fmaf(s, v.w, a.w));
}
__device__ __forceinline__ void f4_store_nt(float* p, float4 v) {
    fx4 w = { v.x, v.y, v.z, v.w };
    __builtin_nontemporal_store(w, reinterpret_cast<fx4*>(p));
}

__global__ __launch_bounds__(256) void dhhp_kernel(
    const float* __restrict__ x,
    const float* __restrict__ gl_ii, const float* __restrict__ gl_ij,
    const float* __restrict__ gl_ji, const float* __restrict__ gl_jj,
    const float* __restrict__ gu_ii, const float* __restrict__ gu_ij,
    const float* __restrict__ gu_ji, const float* __restrict__ gu_jj,
    const float* __restrict__ diag, const int* __restrict__ transform,
    float* __restrict__ out)
{
    // XCD-aware swizzle: 1024 blocks -> each XCD gets a contiguous 128-block
    // chunk == exactly one batch b (8 MB in / 8 MB out): halo reuse stays in L2.
    const int bid  = blockIdx.x;
    const int swz  = (bid & 7) * CPX + (bid >> 3);
    int wid = swz * WPB + (threadIdx.x >> 6);
    wid = __builtin_amdgcn_readfirstlane(wid);       // wave-uniform -> SGPRs
    const int b    = wid >> 9;                       // waves per batch = NN/RPW = 512
    const int j0   = (wid & 511) << 4;               // * RPW
    const int col  = (threadIdx.x & 63) << 2;        // float4 per lane
    const int tr   = *transform;

    const float* xb  = x    + (size_t)b * NN * DD;
    const float* db  = diag + (size_t)b * NN;
    const float* uii = gu_ii + (size_t)b * (NN - 1);
    const float* uij = gu_ij + (size_t)b * (NN - 1);
    const float* uji = gu_ji + (size_t)b * (NN - 1);
    const float* ujj = gu_jj + (size_t)b * (NN - 1);
    const float* lii = gl_ii + (size_t)b * (NN - 1);
    const float* lij = gl_ij + (size_t)b * (NN - 1);
    const float* lji = gl_ji + (size_t)b * (NN - 1);
    const float* ljj = gl_jj + (size_t)b * (NN - 1);
    float* ob = out + (size_t)b * NN * DD;

    auto permRow = [&](int i) -> int {
        return tr ? ((i < NH) ? (i << 1) : (((i - NH) << 1) | 1)) : i;
    };
    auto loadRowI = [&](int i) -> float4 {           // interior: no clamp
        float4 v = f4_load(xb + (size_t)permRow(i) * DD + col);
        if (!tr) v = f4_scale(db[i], v);
        return v;
    };
    auto loadRowC = [&](int i) -> float4 {           // edge: clamped
        int ic = i < 0 ? 0 : (i > NN - 1 ? NN - 1 : i);
        return loadRowI(ic);
    };
    auto yInner = [&](int i, float4 xm, float4 xc, float4 xp) -> float4 {
        float lo  = uji[i - 1];
        float cjj = ujj[i - 1];
        float dm  = cjj * uii[i];
        float hi  = cjj * uij[i];
        float4 r = f4_scale(lo, xm);
        r = f4_fma(dm, xc, r);
        r = f4_fma(hi, xp, r);
        return r;
    };
    auto yAny = [&](int i, float4 xm, float4 xc, float4 xp) -> float4 {
        int ic = i < 0 ? 0 : (i > NN - 1 ? NN - 1 : i);
        if (ic == 0)      return f4_fma(uii[0], xc, f4_scale(uij[0], xp));
        if (ic == NN - 1) return f4_fma(uji[NN - 2], xm, f4_scale(ujj[NN - 2], xc));
        return yInner(ic, xm, xc, xp);
    };
    auto zInner = [&](int j, float4 ym, float4 yc, float4 yp) -> float4 {
        float ci = lii[j];
        float lo = ci * lji[j - 1];
        float dm = ci * ljj[j - 1];
        float hi = lij[j];
        float4 r = f4_scale(lo, ym);
        r = f4_fma(dm, yc, r);
        r = f4_fma(hi, yp, r);
        return r;
    };
    auto zAny = [&](int j, float4 ym, float4 yc, float4 yp) -> float4 {
        if (j == 0)      return f4_fma(lii[0], yc, f4_scale(lij[0], yp));
        if (j == NN - 1) return f4_fma(lji[NN - 2], ym, f4_scale(ljj[NN - 2], yc));
        return zInner(j, ym, yc, yp);
    };
    auto storeRow = [&](int j, float4 z) {
        int jo;
        float4 o;
        if (tr) { o = f4_scale(db[j], z); jo = j; }
        else    { o = z; jo = (j & 1) ? (NH + (j >> 1)) : (j >> 1); }
        // non-temporal: output is never re-read; don't evict input halo from L2
        f4_store_nt(ob + (size_t)jo * DD + col, o);
    };

    const bool interior = (j0 >= 2) && (j0 <= NN - RPW - 2);

    float4 xr[RPW + 4];   // x[j0-2 .. j0+RPW+1]
    float4 yr[RPW + 2];   // y[j0-1 .. j0+RPW]

    if (interior) {
        // 1) ALL window loads issued back-to-back; fence stops the compiler
        //    from sinking any of them below the compute phase.
        #pragma unroll
        for (int t = 0; t < RPW + 4; ++t) xr[t] = loadRowI(j0 - 2 + t);
        __builtin_amdgcn_sched_barrier(0);
        // 2) upper sweep
        #pragma unroll
        for (int t = 0; t < RPW + 2; ++t)
            yr[t] = yInner(j0 - 1 + t, xr[t], xr[t + 1], xr[t + 2]);
        // 3) lower sweep + store
        #pragma unroll
        for (int t = 0; t < RPW; ++t)
            storeRow(j0 + t, zInner(j0 + t, yr[t], yr[t + 1], yr[t + 2]));
    } else {
        #pragma unroll
        for (int t = 0; t < RPW + 4; ++t) xr[t] = loadRowC(j0 - 2 + t);
        __builtin_amdgcn_sched_barrier(0);
        #pragma unroll
        for (int t = 0; t < RPW + 2; ++t)
            yr[t] = yAny(j0 - 1 + t, xr[t], xr[t + 1], xr[t + 2]);
        #pragma unroll
        for (int t = 0; t < RPW; ++t)
            storeRow(j0 + t, zAny(j0 + t, yr[t], yr[t + 1], yr[t + 2]));
    }
}

extern "C" void kernel_launch(void* const* d_in, const int* in_sizes, int n_in,
                              void* d_out, int out_size, void* d_ws, size_t ws_size,
                              hipStream_t stream) {
    const float* x     = (const float*)d_in[0];
    const float* gl_ii = (const float*)d_in[1];
    const float* gl_ij = (const float*)d_in[2];
    const float* gl_ji = (const float*)d_in[3];
    const float* gl_jj = (const float*)d_in[4];
    const float* gu_ii = (const float*)d_in[5];
    const float* gu_ij = (const float*)d_in[6];
    const float* gu_ji = (const float*)d_in[7];
    const float* gu_jj = (const float*)d_in[8];
    const float* diag  = (const float*)d_in[9];
    const int* transform = (const int*)d_in[10];
    float* out = (float*)d_out;

    dim3 grid(NBLK);      // 1024 blocks, 4 waves each
    dim3 block(256);
    hipLaunchKernelGGL(dhhp_kernel, grid, block, 0, stream,
                       x, gl_ii, gl_ij, gl_ji, gl_jj,
                       gu_ii, gu_ij, gu_ji, gu_jj, diag, transform, out);
}

// Round 6
// 31.412 us; speedup vs baseline: 1.0175x; 1.0175x over previous
//
#include <hip/hip_runtime.h>

// Problem constants (match reference: B=8, N=8192, D=256, M=2)
#define NN 8192
#define DD 256
#define NH (NN / 2)
#define BB 8
#define RPW 8            // output rows per wave
#define WPB 4            // waves per block
#define RPB (RPW * WPB)  // 32 output rows per block
#define SROWS (RPB + 4)  // 36 staged rows (halo 2 each side)
#define NBLK (BB * NN / RPB)  // 2048
#define CPX (NBLK / 8)        // 256 blocks per XCD chunk (== one batch b)

__device__ __forceinline__ float4 f4_scale(float s, float4 v) {
    return make_float4(s * v.x, s * v.y, s * v.z, s * v.w);
}
__device__ __forceinline__ float4 f4_fma(float s, float4 v, float4 a) {
    return make_float4(fmaf(s, v.x, a.x), fmaf(s, v.y, a.y),
                       fmaf(s, v.z, a.z), fmaf(s, v.w, a.w));
}

__global__ __launch_bounds__(256) void dhhp_kernel(
    const float* __restrict__ x,
    const float* __restrict__ gl_ii, const float* __restrict__ gl_ij,
    const float* __restrict__ gl_ji, const float* __restrict__ gl_jj,
    const float* __restrict__ gu_ii, const float* __restrict__ gu_ij,
    const float* __restrict__ gu_ji, const float* __restrict__ gu_jj,
    const float* __restrict__ diag, const int* __restrict__ transform,
    float* __restrict__ out)
{
    __shared__ float smem[SROWS * DD];   // 36 KB

    // XCD-aware swizzle: each XCD gets a contiguous 256-block chunk == one batch.
    const int bid = blockIdx.x;
    const int swz = (bid & 7) * CPX + (bid >> 3);
    const int b   = swz >> 8;            // 256 blocks per batch
    const int j0b = (swz & 255) << 5;    // block's first output row (tile of 32)
    const int w   = __builtin_amdgcn_readfirstlane(threadIdx.x >> 6);
    const int col = (threadIdx.x & 63) << 2;   // float4 per lane
    const int tr  = *transform;

    const float* xb  = x    + (size_t)b * NN * DD;
    const float* db  = diag + (size_t)b * NN;
    const float* uii = gu_ii + (size_t)b * (NN - 1);
    const float* uij = gu_ij + (size_t)b * (NN - 1);
    const float* uji = gu_ji + (size_t)b * (NN - 1);
    const float* ujj = gu_jj + (size_t)b * (NN - 1);
    const float* lii = gl_ii + (size_t)b * (NN - 1);
    const float* lij = gl_ij + (size_t)b * (NN - 1);
    const float* lji = gl_ji + (size_t)b * (NN - 1);
    const float* ljj = gl_jj + (size_t)b * (NN - 1);
    float* ob = out + (size_t)b * NN * DD;

    // ---- async stage: 36 rows, 9 per wave, all in flight before the barrier ----
    #pragma unroll
    for (int q = 0; q < SROWS / WPB; ++q) {
        const int s  = w + q * WPB;                 // LDS row slot
        const int i  = j0b - 2 + s;                 // xP row index
        const int ic = i < 0 ? 0 : (i > NN - 1 ? NN - 1 : i);
        const int r  = tr ? ((ic < NH) ? (ic << 1) : (((ic - NH) << 1) | 1)) : ic;
        const float* gp = xb + (size_t)r * DD + col;       // per-lane global src
        float*       lp = smem + s * DD;                   // wave-uniform LDS base
        __builtin_amdgcn_global_load_lds(
            (const __attribute__((address_space(1))) void*)gp,
            (__attribute__((address_space(3))) void*)lp, 16, 0, 0);
    }
    __syncthreads();   // compiler emits s_waitcnt vmcnt(0) before s_barrier

    // ---- compute from LDS ----
    const int j0 = j0b + (w << 3);                  // this wave's first output row

    auto xRow = [&](int i) -> float4 {              // i = xP row index (may be ghost)
        const int s = i - (j0b - 2);
        float4 v = *reinterpret_cast<const float4*>(smem + s * DD + col);
        if (!tr) {
            const int ic = i < 0 ? 0 : (i > NN - 1 ? NN - 1 : i);
            v = f4_scale(db[ic], v);
        }
        return v;
    };
    auto yInner = [&](int i, float4 xm, float4 xc, float4 xp) -> float4 {
        float lo  = uji[i - 1];
        float cjj = ujj[i - 1];
        float dm  = cjj * uii[i];
        float hi  = cjj * uij[i];
        float4 r = f4_scale(lo, xm);
        r = f4_fma(dm, xc, r);
        r = f4_fma(hi, xp, r);
        return r;
    };
    // ghost rows (i<0 / i>N-1) produce wrong-but-unused values
    auto yAny = [&](int i, float4 xm, float4 xc, float4 xp) -> float4 {
        int ic = i < 0 ? 0 : (i > NN - 1 ? NN - 1 : i);
        if (ic == 0)      return f4_fma(uii[0], xc, f4_scale(uij[0], xp));
        if (ic == NN - 1) return f4_fma(uji[NN - 2], xm, f4_scale(ujj[NN - 2], xc));
        return yInner(ic, xm, xc, xp);
    };
    auto zInner = [&](int j, float4 ym, float4 yc, float4 yp) -> float4 {
        float ci = lii[j];
        float lo = ci * lji[j - 1];
        float dm = ci * ljj[j - 1];
        float hi = lij[j];
        float4 r = f4_scale(lo, ym);
        r = f4_fma(dm, yc, r);
        r = f4_fma(hi, yp, r);
        return r;
    };
    auto zAny = [&](int j, float4 ym, float4 yc, float4 yp) -> float4 {
        if (j == 0)      return f4_fma(lii[0], yc, f4_scale(lij[0], yp));
        if (j == NN - 1) return f4_fma(lji[NN - 2], ym, f4_scale(ljj[NN - 2], yc));
        return zInner(j, ym, yc, yp);
    };
    auto storeRow = [&](int j, float4 z) {
        int jo;
        float4 o;
        if (tr) { o = f4_scale(db[j], z); jo = j; }
        else    { o = z; jo = (j & 1) ? (NH + (j >> 1)) : (j >> 1); }
        *reinterpret_cast<float4*>(ob + (size_t)jo * DD + col) = o;
    };

    float4 xr[RPW + 4];   // xP[j0-2 .. j0+RPW+1]
    float4 yr[RPW + 2];   // y[j0-1 .. j0+RPW]

    const bool interior = (j0 >= 2) && (j0 <= NN - RPW - 2);

    if (interior) {
        #pragma unroll
        for (int t = 0; t < RPW + 4; ++t) xr[t] = xRow(j0 - 2 + t);
        #pragma unroll
        for (int t = 0; t < RPW + 2; ++t)
            yr[t] = yInner(j0 - 1 + t, xr[t], xr[t + 1], xr[t + 2]);
        #pragma unroll
        for (int t = 0; t < RPW; ++t)
            storeRow(j0 + t, zInner(j0 + t, yr[t], yr[t + 1], yr[t + 2]));
    } else {
        #pragma unroll
        for (int t = 0; t < RPW + 4; ++t) xr[t] = xRow(j0 - 2 + t);
        #pragma unroll
        for (int t = 0; t < RPW + 2; ++t)
            yr[t] = yAny(j0 - 1 + t, xr[t], xr[t + 1], xr[t + 2]);
        #pragma unroll
        for (int t = 0; t < RPW; ++t)
            storeRow(j0 + t, zAny(j0 + t, yr[t], yr[t + 1], yr[t + 2]));
    }
}

extern "C" void kernel_launch(void* const* d_in, const int* in_sizes, int n_in,
                              void* d_out, int out_size, void* d_ws, size_t ws_size,
                              hipStream_t stream) {
    const float* x     = (const float*)d_in[0];
    const float* gl_ii = (const float*)d_in[1];
    const float* gl_ij = (const float*)d_in[2];
    const float* gl_ji = (const float*)d_in[3];
    const float* gl_jj = (const float*)d_in[4];
    const float* gu_ii = (const float*)d_in[5];
    const float* gu_ij = (const float*)d_in[6];
    const float* gu_ji = (const float*)d_in[7];
    const float* gu_jj = (const float*)d_in[8];
    const float* diag  = (const float*)d_in[9];
    const int* transform = (const int*)d_in[10];
    float* out = (float*)d_out;

    dim3 grid(NBLK);      // 2048 blocks, 4 waves each
    dim3 block(256);
    hipLaunchKernelGGL(dhhp_kernel, grid, block, 0, stream,
                       x, gl_ii, gl_ij, gl_ji, gl_jj,
                       gu_ii, gu_ij, gu_ji, gu_jj, diag, transform, out);
}

// Round 7
// 30.833 us; speedup vs baseline: 1.0366x; 1.0188x over previous
//
#include <hip/hip_runtime.h>

// Problem constants (match reference: B=8, N=8192, D=256, M=2)
#define NN 8192
#define DD 256
#define NH (NN / 2)
#define BB 8
#define RPW 8            // output rows per wave
#define WPB 4            // waves per block
#define NBLK (BB * NN / RPW / WPB)   // 2048
#define CPX (NBLK / 8)               // 256 blocks per XCD chunk (== one batch b)

typedef float fx4 __attribute__((ext_vector_type(4)));

// Forced, unsinkable 16B global load: volatile asm keeps all issued loads
// in flight together (compiler cannot interleave/sink them past the waitcnt).
__device__ __forceinline__ float4 gload4(const float* p) {
    fx4 t;
    asm volatile("global_load_dwordx4 %0, %1, off" : "=v"(t) : "v"(p) : "memory");
    return make_float4(t.x, t.y, t.z, t.w);
}

__device__ __forceinline__ float4 f4_scale(float s, float4 v) {
    return make_float4(s * v.x, s * v.y, s * v.z, s * v.w);
}
__device__ __forceinline__ float4 f4_fma(float s, float4 v, float4 a) {
    return make_float4(fmaf(s, v.x, a.x), fmaf(s, v.y, a.y),
                       fmaf(s, v.z, a.z), fmaf(s, v.w, a.w));
}

__global__ __launch_bounds__(256) void dhhp_kernel(
    const float* __restrict__ x,
    const float* __restrict__ gl_ii, const float* __restrict__ gl_ij,
    const float* __restrict__ gl_ji, const float* __restrict__ gl_jj,
    const float* __restrict__ gu_ii, const float* __restrict__ gu_ij,
    const float* __restrict__ gu_ji, const float* __restrict__ gu_jj,
    const float* __restrict__ diag, const int* __restrict__ transform,
    float* __restrict__ out)
{
    // XCD-aware swizzle: each XCD gets a contiguous 256-block chunk == one batch.
    const int bid = blockIdx.x;
    const int swz = (bid & 7) * CPX + (bid >> 3);
    int wid = swz * WPB + (threadIdx.x >> 6);
    wid = __builtin_amdgcn_readfirstlane(wid);       // wave-uniform -> SGPRs
    const int b   = wid >> 10;                       // waves per batch = NN/RPW = 1024
    const int j0  = (wid & 1023) << 3;               // * RPW
    const int col = (threadIdx.x & 63) << 2;         // float4 per lane
    const int tr  = *transform;

    const float* xb  = x    + (size_t)b * NN * DD;
    const float* db  = diag + (size_t)b * NN;
    const float* uii = gu_ii + (size_t)b * (NN - 1);
    const float* uij = gu_ij + (size_t)b * (NN - 1);
    const float* uji = gu_ji + (size_t)b * (NN - 1);
    const float* ujj = gu_jj + (size_t)b * (NN - 1);
    const float* lii = gl_ii + (size_t)b * (NN - 1);
    const float* lij = gl_ij + (size_t)b * (NN - 1);
    const float* lji = gl_ji + (size_t)b * (NN - 1);
    const float* ljj = gl_jj + (size_t)b * (NN - 1);
    float* ob = out + (size_t)b * NN * DD;

    // ---- forced register batch: 12 addresses, 12 loads, one wait ----
    int ics[RPW + 4];
    const float* ap[RPW + 4];
    #pragma unroll
    for (int t = 0; t < RPW + 4; ++t) {
        int i  = j0 - 2 + t;
        int ic = i < 0 ? 0 : (i > NN - 1 ? NN - 1 : i);
        ics[t] = ic;
        int r  = tr ? ((ic < NH) ? (ic << 1) : (((ic - NH) << 1) | 1)) : ic;
        ap[t]  = xb + (size_t)r * DD + col;
    }
    float4 xr[RPW + 4];
    #pragma unroll
    for (int t = 0; t < RPW + 4; ++t) xr[t] = gload4(ap[t]);
    asm volatile("s_waitcnt vmcnt(0)" ::: "memory");

    if (!tr) {
        #pragma unroll
        for (int t = 0; t < RPW + 4; ++t) xr[t] = f4_scale(db[ics[t]], xr[t]);
    }

    // ---- compute ----
    auto yInner = [&](int i, float4 xm, float4 xc, float4 xp) -> float4 {
        float lo  = uji[i - 1];
        float cjj = ujj[i - 1];
        float dm  = cjj * uii[i];
        float hi  = cjj * uij[i];
        float4 r = f4_scale(lo, xm);
        r = f4_fma(dm, xc, r);
        r = f4_fma(hi, xp, r);
        return r;
    };
    // ghost rows (i<0 / i>N-1 after clamp) produce wrong-but-unused values
    auto yAny = [&](int i, float4 xm, float4 xc, float4 xp) -> float4 {
        int ic = i < 0 ? 0 : (i > NN - 1 ? NN - 1 : i);
        if (ic == 0)      return f4_fma(uii[0], xc, f4_scale(uij[0], xp));
        if (ic == NN - 1) return f4_fma(uji[NN - 2], xm, f4_scale(ujj[NN - 2], xc));
        return yInner(ic, xm, xc, xp);
    };
    auto zInner = [&](int j, float4 ym, float4 yc, float4 yp) -> float4 {
        float ci = lii[j];
        float lo = ci * lji[j - 1];
        float dm = ci * ljj[j - 1];
        float hi = lij[j];
        float4 r = f4_scale(lo, ym);
        r = f4_fma(dm, yc, r);
        r = f4_fma(hi, yp, r);
        return r;
    };
    auto zAny = [&](int j, float4 ym, float4 yc, float4 yp) -> float4 {
        if (j == 0)      return f4_fma(lii[0], yc, f4_scale(lij[0], yp));
        if (j == NN - 1) return f4_fma(lji[NN - 2], ym, f4_scale(ljj[NN - 2], yc));
        return zInner(j, ym, yc, yp);
    };
    auto storeRow = [&](int j, float4 z) {
        int jo;
        float4 o;
        if (tr) { o = f4_scale(db[j], z); jo = j; }
        else    { o = z; jo = (j & 1) ? (NH + (j >> 1)) : (j >> 1); }
        *reinterpret_cast<float4*>(ob + (size_t)jo * DD + col) = o;
    };

    float4 yr[RPW + 2];
    const bool interior = (j0 >= 2) && (j0 <= NN - RPW - 2);

    if (interior) {
        #pragma unroll
        for (int t = 0; t < RPW + 2; ++t)
            yr[t] = yInner(j0 - 1 + t, xr[t], xr[t + 1], xr[t + 2]);
        #pragma unroll
        for (int t = 0; t < RPW; ++t)
            storeRow(j0 + t, zInner(j0 + t, yr[t], yr[t + 1], yr[t + 2]));
    } else {
        #pragma unroll
        for (int t = 0; t < RPW + 2; ++t)
            yr[t] = yAny(j0 - 1 + t, xr[t], xr[t + 1], xr[t + 2]);
        #pragma unroll
        for (int t = 0; t < RPW; ++t)
            storeRow(j0 + t, zAny(j0 + t, yr[t], yr[t + 1], yr[t + 2]));
    }
}

extern "C" void kernel_launch(void* const* d_in, const int* in_sizes, int n_in,
                              void* d_out, int out_size, void* d_ws, size_t ws_size,
                              hipStream_t stream) {
    const float* x     = (const float*)d_in[0];
    const float* gl_ii = (const float*)d_in[1];
    const float* gl_ij = (const float*)d_in[2];
    const float* gl_ji = (const float*)d_in[3];
    const float* gl_jj = (const float*)d_in[4];
    const float* gu_ii = (const float*)d_in[5];
    const float* gu_ij = (const float*)d_in[6];
    const float* gu_ji = (const float*)d_in[7];
    const float* gu_jj = (const float*)d_in[8];
    const float* diag  = (const float*)d_in[9];
    const int* transform = (const int*)d_in[10];
    float* out = (float*)d_out;

    dim3 grid(NBLK);      // 2048 blocks, 4 waves each
    dim3 block(256);
    hipLaunchKernelGGL(dhhp_kernel, grid, block, 0, stream,
                       x, gl_ii, gl_ij, gl_ji, gl_jj,
                       gu_ii, gu_ij, gu_ji, gu_jj, diag, transform, out);
}